// Round 2
// baseline (47128.436 us; speedup 1.0000x reference)
//
#include <hip/hip_runtime.h>
#include <hip/hip_cooperative_groups.h>

namespace cg = cooperative_groups;

// LSTM_71167608094989: 2-layer LSTM, T=512, B=64, I=H=1024, eval mode.
// Round 2: persistent cooperative kernel. 256 blocks x 512 threads (1 block/CU,
// 139KB LDS). Weights live in LDS in MFMA-B-fragment order (loaded once).
// Cell state c lives in registers. grid.sync() between steps. Both layers run
// concurrently, diagonally pipelined (layer0 step s, layer1 step s-1).

typedef _Float16 h8_t __attribute__((ext_vector_type(8)));
typedef _Float16 h4_t __attribute__((ext_vector_type(4)));
typedef float f4_t __attribute__((ext_vector_type(4)));

#define T_STEPS 512
#define BATCH 64
#define HID 1024
#define STEP_ELEMS (BATCH * HID)   // 65536

// ---------------- conversion kernel ----------------

__global__ void k_f32_to_f16(const float* __restrict__ src, _Float16* __restrict__ dst) {
    size_t i = ((size_t)blockIdx.x * blockDim.x + threadIdx.x) * 4;
    float4 v = *(const float4*)(src + i);
    h4_t h = { (_Float16)v.x, (_Float16)v.y, (_Float16)v.z, (_Float16)v.w };
    *(h4_t*)(dst + i) = h;
}

// ---------------- persistent LSTM kernel ----------------

__device__ __forceinline__ float sigmf(float x) { return 1.0f / (1.0f + __expf(-x)); }

struct Params {
    const _Float16* x16;
    const float *w_ih0, *w_hh0, *b_ih0, *b_hh0;
    const float *w_ih1, *w_hh1, *b_ih1, *b_hh1;
    _Float16 *h1, *h2;   // double buffers [2][STEP_ELEMS] fp16
    float* out;          // [T][STEP_ELEMS] fp32
};

// LDS layout:
//   wfrag: [2 ntile][64 kk][64 lane][8 f16]  = 128 KB  (B fragments, K=2048)
//   gates: [64 rows][33 f32]                 = 8448 B
// block b (0..127) of layer L owns units u0=8b..8b+7 -> 32 gate columns:
//   col c (0..31): gate g = c>>3, unit uu = c&7  (ntile = c>>4)
__global__ __launch_bounds__(512, 1) void lstm_persist(Params p) {
    extern __shared__ char smem[];
    _Float16* wfrag = (_Float16*)smem;                  // 131072 B
    float* gates = (float*)(smem + 131072);             // 64*33*4 B

    const int tid = threadIdx.x;
    const int layer = blockIdx.x & 1;
    const int b = blockIdx.x >> 1;
    const int u0 = b * 8;

    const float* wih = layer ? p.w_ih1 : p.w_ih0;
    const float* whh = layer ? p.w_hh1 : p.w_hh0;
    const float* bih = layer ? p.b_ih1 : p.b_ih0;
    const float* bhh = layer ? p.b_hh1 : p.b_hh0;

    // ---- stage weights into LDS in B-fragment order (once) ----
    // chunk ch = c*256 + k8 : col c in [0,32), k8 = 8-elem chunk along K in [0,256)
    // element k = k8*8 + j : kk = k>>5 = k8>>2, q = (k>>3)&3 = k8&3, j = k&7
    // fragment lane = q*16 + col(c&15); h8 index = (ntile*64+kk)*64 + q*16 + col
    for (int iter = 0; iter < 16; ++iter) {
        int ch = iter * 512 + tid;
        int c = ch >> 8;
        int k8 = ch & 255;
        int g = c >> 3, uu = c & 7;
        const float* wsrc = (k8 < 128) ? wih : whh;
        const float* src = wsrc + (size_t)(g * 1024 + u0 + uu) * 1024 + (size_t)(k8 & 127) * 8;
        float4 v0 = *(const float4*)src;
        float4 v1 = *(const float4*)(src + 4);
        h8_t hv = { (_Float16)v0.x, (_Float16)v0.y, (_Float16)v0.z, (_Float16)v0.w,
                    (_Float16)v1.x, (_Float16)v1.y, (_Float16)v1.z, (_Float16)v1.w };
        int ntile = c >> 4, col = c & 15, kk = k8 >> 2, q = k8 & 3;
        ((h8_t*)wfrag)[(ntile * 64 + kk) * 64 + q * 16 + col] = hv;
    }

    // ---- per-thread cell state: thread owns cell (row = tid>>3, unit = u0 + (tid&7)) ----
    const int row = tid >> 3;
    const int uu_c = tid & 7;
    const int unit = u0 + uu_c;
    const float bi = bih[unit] + bhh[unit];
    const float bf = bih[1024 + unit] + bhh[1024 + unit];
    const float bg = bih[2048 + unit] + bhh[2048 + unit];
    const float bo = bih[3072 + unit] + bhh[3072 + unit];
    float c_st = 0.0f;

    // ---- MFMA tile assignment: 8 waves = 4 mtiles x 2 ntiles ----
    const int wave = tid >> 6, lane = tid & 63;
    const int mtile = wave >> 1, ntile = wave & 1;
    const int q = lane >> 4, m16 = lane & 15;
    const int r = mtile * 16 + m16;              // batch row for A fragments
    const h8_t* bp = (const h8_t*)wfrag + ntile * 64 * 64 + lane;

    cg::grid_group grid = cg::this_grid();
    __syncthreads();  // weights staged

    for (int s = 0; s <= T_STEPS; ++s) {
        const int t = layer ? (s - 1) : s;
        const bool active = layer ? (s >= 1) : (s < T_STEPS);
        if (active) {
            const _Float16* xsrc = layer ? (p.h1 + (size_t)(t & 1) * STEP_ELEMS)
                                         : (p.x16 + (size_t)t * STEP_ELEMS);
            const _Float16* hsrc = (layer ? p.h2 : p.h1) + (size_t)((t + 1) & 1) * STEP_ELEMS;
            f4_t acc = {};
            // phase 1: x part (K 0..1024)
            {
                const _Float16* ax = xsrc + (size_t)r * 1024 + q * 8;
#pragma unroll 8
                for (int kk = 0; kk < 32; ++kk) {
                    h8_t a = *(const h8_t*)(ax + kk * 32);
                    acc = __builtin_amdgcn_mfma_f32_16x16x32_f16(a, bp[kk * 64], acc, 0, 0, 0);
                }
            }
            // phase 2: h part (K 1024..2048); h_prev == 0 when t == 0
            if (t > 0) {
                const _Float16* ah = hsrc + (size_t)r * 1024 + q * 8;
#pragma unroll 8
                for (int kk = 0; kk < 32; ++kk) {
                    h8_t a = *(const h8_t*)(ah + kk * 32);
                    acc = __builtin_amdgcn_mfma_f32_16x16x32_f16(a, bp[(32 + kk) * 64], acc, 0, 0, 0);
                }
            }
            // C/D layout: row_in_tile = q*4+ri, col = m16
#pragma unroll
            for (int ri = 0; ri < 4; ++ri)
                gates[(mtile * 16 + q * 4 + ri) * 33 + ntile * 16 + m16] = acc[ri];
        }
        __syncthreads();
        if (active) {
            float iv = gates[row * 33 + uu_c] + bi;
            float fv = gates[row * 33 + 8 + uu_c] + bf;
            float gv = gates[row * 33 + 16 + uu_c] + bg;
            float ov = gates[row * 33 + 24 + uu_c] + bo;
            c_st = sigmf(fv) * c_st + sigmf(iv) * tanhf(gv);
            float hn = sigmf(ov) * tanhf(c_st);
            size_t idx = (size_t)row * 1024 + unit;
            if (layer == 0) {
                p.h1[(size_t)(t & 1) * STEP_ELEMS + idx] = (_Float16)hn;
            } else {
                p.h2[(size_t)(t & 1) * STEP_ELEMS + idx] = (_Float16)hn;
                p.out[(size_t)t * STEP_ELEMS + idx] = hn;
            }
        }
        __threadfence();
        grid.sync();
    }
}

// ---------------- host orchestration ----------------

extern "C" void kernel_launch(void* const* d_in, const int* in_sizes, int n_in,
                              void* d_out, int out_size, void* d_ws, size_t ws_size,
                              hipStream_t stream) {
    const float* input = (const float*)d_in[0];

    char* p = (char*)d_ws;
    _Float16* x16 = (_Float16*)p;  p += (size_t)T_STEPS * STEP_ELEMS * 2;  // 67 MB
    _Float16* h1  = (_Float16*)p;  p += (size_t)2 * STEP_ELEMS * 2;
    _Float16* h2  = (_Float16*)p;  p += (size_t)2 * STEP_ELEMS * 2;

    // fp32 -> fp16 conversion of the input sequence
    k_f32_to_f16<<<(T_STEPS * STEP_ELEMS / 4) / 256, 256, 0, stream>>>(input, x16);

    Params prm;
    prm.x16 = x16;
    prm.w_ih0 = (const float*)d_in[1];
    prm.w_hh0 = (const float*)d_in[2];
    prm.b_ih0 = (const float*)d_in[3];
    prm.b_hh0 = (const float*)d_in[4];
    prm.w_ih1 = (const float*)d_in[5];
    prm.w_hh1 = (const float*)d_in[6];
    prm.b_ih1 = (const float*)d_in[7];
    prm.b_hh1 = (const float*)d_in[8];
    prm.h1 = h1;
    prm.h2 = h2;
    prm.out = (float*)d_out;

    const unsigned smem_bytes = 131072 + 64 * 33 * 4;  // 139520
    static bool attr_set = false;
    if (!attr_set) {
        hipFuncSetAttribute((const void*)lstm_persist,
                            hipFuncAttributeMaxDynamicSharedMemorySize, smem_bytes);
        attr_set = true;
    }

    void* args[] = { &prm };
    hipLaunchCooperativeKernel((const void*)lstm_persist, dim3(256), dim3(512),
                               args, smem_bytes, stream);
}